// Round 1
// baseline (206.912 us; speedup 1.0000x reference)
//
#include <hip/hip_runtime.h>
#include <hip/hip_bf16.h>
#include <cstdint>

typedef __attribute__((ext_vector_type(8))) __bf16 bf16x8;
typedef __attribute__((ext_vector_type(4))) float f32x4;

static __device__ __forceinline__ unsigned short f2bf(float f) {
  return __builtin_bit_cast(unsigned short, (__bf16)f);
}
static __device__ __forceinline__ unsigned pack2(float a, float b) {
  return (unsigned)f2bf(a) | ((unsigned)f2bf(b) << 16);
}

// ---------------- small prep kernels ----------------

__global__ void transpose_w_kernel(const float* __restrict__ W1, const float* __restrict__ W2,
                                   unsigned short* __restrict__ W1t, unsigned short* __restrict__ W2t) {
  int i = blockIdx.x * 256 + threadIdx.x;      // 65536 total
  int k = i >> 8, n = i & 255;
  W1t[n * 256 + k] = f2bf(W1[k * 256 + n]);
  W2t[n * 256 + k] = f2bf(W2[k * 256 + n]);
}

// x2 = linear2x(h) along nodes; emit bf16 x2 and fp32 row squared-norms
__global__ void upsample_kernel(const float* __restrict__ h, unsigned short* __restrict__ x2b,
                                float* __restrict__ sq) {
  int o = blockIdx.x;        // 0..8191
  int c = threadIdx.x;       // 0..255
  float s = (o + 0.5f) * 0.5f - 0.5f;
  s = fminf(fmaxf(s, 0.0f), 4095.0f);
  float fl = floorf(s);
  int i0 = (int)fl;
  int i1 = min(i0 + 1, 4095);
  float w = s - fl;
  float v = h[i0 * 256 + c] * (1.0f - w) + h[i1 * 256 + c] * w;
  x2b[o * 256 + c] = f2bf(v);
  float p = v * v;
  #pragma unroll
  for (int m = 32; m > 0; m >>= 1) p += __shfl_down(p, m, 64);
  __shared__ float red[4];
  if ((threadIdx.x & 63) == 0) red[threadIdx.x >> 6] = p;
  __syncthreads();
  if (threadIdx.x == 0) sq[o] = (red[0] + red[1]) + (red[2] + red[3]);
}

__global__ void gather_kernel(const float* __restrict__ support,
                              const unsigned long long* __restrict__ packedv,
                              float* __restrict__ out) {
  int gid = blockIdx.x * 256 + threadIdx.x;
  int row = gid >> 6;
  int c4 = (gid & 63) * 4;
  unsigned idx = (unsigned)(packedv[row] & 0xffffffffull);
  *(float4*)&out[(size_t)row * 256 + c4] = *(const float4*)&support[(size_t)idx * 256 + c4];
}

// ---------------- unified GEMM-NT (C = A * B^T), bf16 MFMA ----------------
// A: [M][K] (fp32 if AF32 else bf16), lda=K elems. B: [N][K] bf16, ldb=K elems.
// EPI 0: Cf[m][n] fp32 (ld=N).  EPI 1: Ct[n][m] bf16 (ld=M).
// EPI 2: fused d2 row-argmin -> packed[m] = atomicMin((f32bits(d2)<<32)|j).
template <int BM, int BN, int WAVES_M, int EPI, bool AF32>
__launch_bounds__(256)
__global__ void gemm_nt_kernel(const void* __restrict__ Ap, int lda,
                               const unsigned short* __restrict__ Bp, int ldb,
                               int M, int N, int K,
                               float* __restrict__ Cf,
                               unsigned short* __restrict__ Ct,
                               const float* __restrict__ sq,
                               unsigned long long* __restrict__ packedv) {
  constexpr int BK = 64;                 // 128B rows in LDS, 8x16B chunks
  constexpr int WAVES_N = 4 / WAVES_M;
  constexpr int WM = BM / WAVES_M;
  constexpr int WN = BN / WAVES_N;
  constexpr int FM = WM / 16;
  constexpr int FN = WN / 16;
  static_assert(BM % 32 == 0 && BN % 32 == 0, "staging geometry");

  __shared__ alignas(16) unsigned short As[BM * BK];
  __shared__ alignas(16) unsigned short Bs[BN * BK];

  const int tid = threadIdx.x;
  const int wid = tid >> 6;
  const int lane = tid & 63;
  const int g = lane >> 4;       // k-group 0..3
  const int lr = lane & 15;      // row-of-A / col-of-B within fragment
  const int wr = wid / WAVES_N;
  const int wc = wid % WAVES_N;
  const int m0 = blockIdx.x * BM;
  const int n0 = blockIdx.y * BN;

  f32x4 acc[FM][FN];
  const f32x4 fzero = {0.0f, 0.0f, 0.0f, 0.0f};
  #pragma unroll
  for (int i = 0; i < FM; ++i)
    #pragma unroll
    for (int j = 0; j < FN; ++j) acc[i][j] = fzero;

  for (int k0 = 0; k0 < K; k0 += BK) {
    // ---- stage A tile [BM][BK] ----
    if constexpr (AF32) {
      // reg-staged fp32 -> bf16, XOR-swizzled chunks; LDS writes are linear per tid
      const float* A = (const float*)Ap;
      #pragma unroll
      for (int rr = 0; rr < BM / 32; ++rr) {
        int row = rr * 32 + (tid >> 3);
        int cp = tid & 7;                  // LDS chunk
        int sc = cp ^ (row & 7);           // source chunk (involution)
        const float* src = A + (size_t)(m0 + row) * lda + k0 + sc * 8;
        float4 v0 = *(const float4*)src;
        float4 v1 = *(const float4*)(src + 4);
        uint4 pk = { pack2(v0.x, v0.y), pack2(v0.z, v0.w),
                     pack2(v1.x, v1.y), pack2(v1.z, v1.w) };
        *(uint4*)&As[row * BK + cp * 8] = pk;
      }
    } else {
      const unsigned short* A = (const unsigned short*)Ap;
      #pragma unroll
      for (int t = 0; t < BM / 32; ++t) {
        int s = t * 256 + tid;             // 16B slot id
        int row = s >> 3;
        int cp = s & 7;
        int sc = cp ^ (row & 7);           // pre-swizzled GLOBAL source (rule #21)
        const unsigned short* src = A + (size_t)(m0 + row) * lda + k0 + sc * 8;
        __builtin_amdgcn_global_load_lds(
            (const __attribute__((address_space(1))) void*)src,
            (__attribute__((address_space(3))) void*)&As[(t * 256 + wid * 64) * 8],
            16, 0, 0);
      }
    }
    // ---- stage B tile [BN][BK] (always bf16, global_load_lds 16B) ----
    #pragma unroll
    for (int t = 0; t < BN / 32; ++t) {
      int s = t * 256 + tid;
      int row = s >> 3;
      int cp = s & 7;
      int sc = cp ^ (row & 7);
      const unsigned short* src = Bp + (size_t)(n0 + row) * ldb + k0 + sc * 8;
      __builtin_amdgcn_global_load_lds(
          (const __attribute__((address_space(1))) void*)src,
          (__attribute__((address_space(3))) void*)&Bs[(t * 256 + wid * 64) * 8],
          16, 0, 0);
    }
    __syncthreads();   // drains vmcnt+lgkmcnt (compiler-emitted)

    // ---- compute: 2 k-slices of 32 ----
    #pragma unroll
    for (int kk = 0; kk < BK / 32; ++kk) {
      bf16x8 a[FM], b[FN];
      #pragma unroll
      for (int i = 0; i < FM; ++i) {
        int row = wr * WM + i * 16 + lr;
        int ch = (kk * 4 + g) ^ (row & 7);
        a[i] = *(const bf16x8*)&As[row * BK + ch * 8];
      }
      #pragma unroll
      for (int j = 0; j < FN; ++j) {
        int row = wc * WN + j * 16 + lr;
        int ch = (kk * 4 + g) ^ (row & 7);
        b[j] = *(const bf16x8*)&Bs[row * BK + ch * 8];
      }
      #pragma unroll
      for (int i = 0; i < FM; ++i)
        #pragma unroll
        for (int j = 0; j < FN; ++j)
          acc[i][j] = __builtin_amdgcn_mfma_f32_16x16x32_bf16(a[i], b[j], acc[i][j], 0, 0, 0);
    }
    __syncthreads();
  }

  // ---- epilogue ----
  // C/D frag map (m89-verified): col = lane&15, row = (lane>>4)*4 + reg
  const int rowb = wr * WM;
  const int colb = wc * WN;
  if constexpr (EPI == 0) {
    #pragma unroll
    for (int i = 0; i < FM; ++i) {
      int mrow = m0 + rowb + i * 16 + g * 4;
      #pragma unroll
      for (int j = 0; j < FN; ++j) {
        int col = n0 + colb + j * 16 + lr;
        #pragma unroll
        for (int r = 0; r < 4; ++r)
          Cf[(size_t)(mrow + r) * N + col] = acc[i][j][r];
      }
    }
  } else if constexpr (EPI == 1) {
    #pragma unroll
    for (int i = 0; i < FM; ++i) {
      int mrow = m0 + rowb + i * 16 + g * 4;
      #pragma unroll
      for (int j = 0; j < FN; ++j) {
        int col = n0 + colb + j * 16 + lr;
        ushort4 st;
        st.x = f2bf(acc[i][j][0]);
        st.y = f2bf(acc[i][j][1]);
        st.z = f2bf(acc[i][j][2]);
        st.w = f2bf(acc[i][j][3]);
        *(ushort4*)&Ct[(size_t)col * M + mrow] = st;
      }
    }
  } else {
    // fused pairwise-d2 row argmin
    float sqj[FN];
    int jcol[FN];
    #pragma unroll
    for (int j = 0; j < FN; ++j) {
      jcol[j] = n0 + colb + j * 16 + lr;
      sqj[j] = sq[jcol[j]];
    }
    #pragma unroll
    for (int i = 0; i < FM; ++i) {
      #pragma unroll
      for (int r = 0; r < 4; ++r) {
        int irow = m0 + rowb + i * 16 + g * 4 + r;
        float sqi = sq[irow];
        float v = 3.402823466e38f;
        int jb = 0;
        #pragma unroll
        for (int j = 0; j < FN; ++j) {
          float d2 = sqi + sqj[j] - 2.0f * acc[i][j][r];
          if (jcol[j] == irow) d2 = 3.402823466e38f;   // exclude diagonal
          if (d2 < v) { v = d2; jb = jcol[j]; }        // ascending j: strict < keeps first
        }
        // butterfly min across the 16 lanes sharing this row (same lane>>4 group)
        #pragma unroll
        for (int m = 1; m < 16; m <<= 1) {
          float vo = __shfl_xor(v, m, 64);
          int jo = __shfl_xor(jb, m, 64);
          if (vo < v || (vo == v && jo < jb)) { v = vo; jb = jo; }
        }
        if (lr == 0) {
          unsigned long long key =
              ((unsigned long long)__float_as_uint(v) << 32) | (unsigned)jb;
          atomicMin(&packedv[irow], key);
        }
      }
    }
  }
}

// ---------------- launch ----------------

extern "C" void kernel_launch(void* const* d_in, const int* in_sizes, int n_in,
                              void* d_out, int out_size, void* d_ws, size_t ws_size,
                              hipStream_t stream) {
  (void)in_sizes; (void)n_in; (void)out_size; (void)ws_size;
  const float* x   = (const float*)d_in[0];   // [4096][256]
  const float* adj = (const float*)d_in[1];   // [4096][4096]
  const float* W1  = (const float*)d_in[2];   // [256][256]
  const float* W2  = (const float*)d_in[3];   // [256][256]
  float* out = (float*)d_out;                 // [8192][256]

  char* p = (char*)d_ws;                      // ~18.4 MB total
  unsigned short* Tt       = (unsigned short*)p;      p += 4096 * 256 * 2;  // (x@W1)^T [256][4096]
  float* hbuf              = (float*)p;               p += 4096 * 256 * 4;  // adj@T
  unsigned short* x2b      = (unsigned short*)p;      p += 8192 * 256 * 2;  // upsampled, bf16
  float* sqv               = (float*)p;               p += 8192 * 4;        // row |x2|^2
  unsigned long long* pck  = (unsigned long long*)p;  p += 8192 * 8;        // packed argmin
  float* support           = (float*)p;               p += 8192 * 256 * 4;  // x2@W2
  unsigned short* W1t      = (unsigned short*)p;      p += 256 * 256 * 2;
  unsigned short* W2t      = (unsigned short*)p;      p += 256 * 256 * 2;

  hipMemsetAsync(pck, 0xFF, 8192 * 8, stream);        // +inf keys for atomicMin
  transpose_w_kernel<<<256, 256, 0, stream>>>(W1, W2, W1t, W2t);

  // Tt = (x @ W1)^T : M=4096 N=256 K=256, A=x fp32 reg-staged
  gemm_nt_kernel<128, 64, 4, 1, true><<<dim3(32, 4), 256, 0, stream>>>(
      x, 256, W1t, 256, 4096, 256, 256, nullptr, Tt, nullptr, nullptr);

  // h = adj @ T : M=4096 N=256 K=4096. BN=256 => adj read exactly once (64 MB).
  gemm_nt_kernel<32, 256, 1, 0, true><<<dim3(128, 1), 256, 0, stream>>>(
      adj, 4096, Tt, 4096, 4096, 256, 4096, hbuf, nullptr, nullptr, nullptr);

  upsample_kernel<<<8192, 256, 0, stream>>>(hbuf, x2b, sqv);

  // Gram(x2) + fused d2 argmin : M=N=8192, K=256
  gemm_nt_kernel<128, 128, 2, 2, false><<<dim3(64, 64), 256, 0, stream>>>(
      x2b, 256, x2b, 256, 8192, 8192, 256, nullptr, nullptr, sqv, pck);

  // support = x2 @ W2 : M=8192 N=256 K=256
  gemm_nt_kernel<128, 64, 4, 0, false><<<dim3(64, 4), 256, 0, stream>>>(
      x2b, 256, W2t, 256, 8192, 256, 256, support, nullptr, nullptr, nullptr);

  gather_kernel<<<2048, 256, 0, stream>>>(support, pck, out);
}

// Round 2
// 153.873 us; speedup vs baseline: 1.3447x; 1.3447x over previous
//
#include <hip/hip_runtime.h>
#include <hip/hip_bf16.h>
#include <cstdint>

typedef __attribute__((ext_vector_type(8))) __bf16 bf16x8;
typedef __attribute__((ext_vector_type(4))) float f32x4;

static __device__ __forceinline__ unsigned short f2bf(float f) {
  return __builtin_bit_cast(unsigned short, (__bf16)f);
}
static __device__ __forceinline__ unsigned pack2(float a, float b) {
  return (unsigned)f2bf(a) | ((unsigned)f2bf(b) << 16);
}

// ---------------- small prep kernels ----------------

__global__ void transpose_w_kernel(const float* __restrict__ W1, const float* __restrict__ W2,
                                   unsigned short* __restrict__ W1t, unsigned short* __restrict__ W2t) {
  int i = blockIdx.x * 256 + threadIdx.x;
  int k = i >> 8, n = i & 255;
  W1t[n * 256 + k] = f2bf(W1[k * 256 + n]);
  W2t[n * 256 + k] = f2bf(W2[k * 256 + n]);
}

__global__ void upsample_kernel(const float* __restrict__ h, unsigned short* __restrict__ x2b,
                                float* __restrict__ sq) {
  int o = blockIdx.x;
  int c = threadIdx.x;
  float s = (o + 0.5f) * 0.5f - 0.5f;
  s = fminf(fmaxf(s, 0.0f), 4095.0f);
  float fl = floorf(s);
  int i0 = (int)fl;
  int i1 = min(i0 + 1, 4095);
  float w = s - fl;
  float v = h[i0 * 256 + c] * (1.0f - w) + h[i1 * 256 + c] * w;
  x2b[o * 256 + c] = f2bf(v);
  float p = v * v;
  #pragma unroll
  for (int m = 32; m > 0; m >>= 1) p += __shfl_down(p, m, 64);
  __shared__ float red[4];
  if ((threadIdx.x & 63) == 0) red[threadIdx.x >> 6] = p;
  __syncthreads();
  if (threadIdx.x == 0) sq[o] = (red[0] + red[1]) + (red[2] + red[3]);
}

__global__ void gather_kernel(const float* __restrict__ support,
                              const unsigned* __restrict__ pck,
                              float* __restrict__ out) {
  int gid = blockIdx.x * 256 + threadIdx.x;
  int row = gid >> 6;
  int c4 = (gid & 63) * 4;
  unsigned idx = pck[row] & 0x1FFFu;
  *(float4*)&out[(size_t)row * 256 + c4] = *(const float4*)&support[(size_t)idx * 256 + c4];
}

// ---------------- unified GEMM-NT (C = A * B^T), bf16 MFMA, 2-phase pipelined ----
// A: [M][K] (fp32 if AF32 else bf16), lda=K. B: [N][K] bf16, ldb=K.
// EPI 0: Cf[m][n] fp32.  EPI 1: Ct[n][m] bf16 (transposed store).
// EPI 2: symmetric fused d2 argmin. grid.x = triangular index over (bi>=bj);
//        u32 keys (d2bits&0xFFFFE000)|index, row-side AND col-side atomicMin.
template <int BM, int BN, int WAVES_M, int EPI, bool AF32>
__launch_bounds__(256)
__global__ void gemm_nt_kernel(const void* __restrict__ Ap, int lda,
                               const unsigned short* __restrict__ Bp, int ldb,
                               int M, int N, int K,
                               float* __restrict__ Cf,
                               unsigned short* __restrict__ Ct,
                               const float* __restrict__ sq,
                               unsigned* __restrict__ pck) {
  constexpr int BK = 64;                 // 128B LDS rows, 8x16B chunks
  constexpr int WAVES_N = 4 / WAVES_M;
  constexpr int WM = BM / WAVES_M;
  constexpr int WN = BN / WAVES_N;
  constexpr int FM = WM / 16;
  constexpr int FN = WN / 16;
  constexpr int ASLOT = BM * 8;          // 16B dst chunks in an A tile
  constexpr int AITER = (ASLOT + 255) / 256;
  constexpr int BITER = (BN * 8) / 256;

  __shared__ alignas(16) unsigned short As0[BM * BK], As1[BM * BK];
  __shared__ alignas(16) unsigned short Bs0[BN * BK], Bs1[BN * BK];

  const int tid = threadIdx.x;
  const int wid = tid >> 6;
  const int lane = tid & 63;
  const int g = lane >> 4;
  const int lr = lane & 15;
  const int wr = wid / WAVES_N;
  const int wc = wid % WAVES_N;

  int bx, by;
  if constexpr (EPI == 2) {
    int t = blockIdx.x;                 // triangular decode, bj <= bi
    int bi = (int)((sqrtf(8.0f * (float)t + 1.0f) - 1.0f) * 0.5f);
    while ((bi + 1) * (bi + 2) / 2 <= t) ++bi;
    while (bi * (bi + 1) / 2 > t) --bi;
    bx = bi;
    by = t - bi * (bi + 1) / 2;
  } else {
    bx = blockIdx.x;
    by = blockIdx.y;
  }
  const int m0 = bx * BM;
  const int n0 = by * BN;

  f32x4 acc[FM][FN];
  const f32x4 fzero = {0.0f, 0.0f, 0.0f, 0.0f};
  #pragma unroll
  for (int i = 0; i < FM; ++i)
    #pragma unroll
    for (int j = 0; j < FN; ++j) acc[i][j] = fzero;

  float4 ar[AITER][2];                   // early-issued A regs (AF32 path)

  // issue A loads for K-slice k0 (AF32: global->reg; else: global_load_lds direct)
  auto issueA = [&](int k0, unsigned short* Asd) {
    if constexpr (AF32) {
      const float* A = (const float*)Ap;
      #pragma unroll
      for (int t = 0; t < AITER; ++t) {
        int s = t * 256 + tid;
        if (ASLOT % 256 == 0 || s < ASLOT) {
          int row = s >> 3, cp = s & 7, sc = cp ^ (row & 7);
          const float* src = A + (size_t)(m0 + row) * (size_t)lda + k0 + sc * 8;
          ar[t][0] = *(const float4*)src;
          ar[t][1] = *(const float4*)(src + 4);
        }
      }
    } else {
      const unsigned short* A = (const unsigned short*)Ap;
      #pragma unroll
      for (int t = 0; t < AITER; ++t) {
        int s = t * 256 + tid;
        int row = s >> 3, cp = s & 7, sc = cp ^ (row & 7);
        const unsigned short* src = A + (size_t)(m0 + row) * (size_t)lda + k0 + sc * 8;
        __builtin_amdgcn_global_load_lds(
            (const __attribute__((address_space(1))) void*)src,
            (__attribute__((address_space(3))) void*)(Asd + (size_t)(t * 256 + wid * 64) * 8),
            16, 0, 0);
      }
    }
  };
  // finish A staging (AF32 only): convert + ds_write (after compute of current tile)
  auto writeA = [&](unsigned short* Asd) {
    if constexpr (AF32) {
      #pragma unroll
      for (int t = 0; t < AITER; ++t) {
        int s = t * 256 + tid;
        if (ASLOT % 256 == 0 || s < ASLOT) {
          int row = s >> 3, cp = s & 7;
          uint4 pk = { pack2(ar[t][0].x, ar[t][0].y), pack2(ar[t][0].z, ar[t][0].w),
                       pack2(ar[t][1].x, ar[t][1].y), pack2(ar[t][1].z, ar[t][1].w) };
          *(uint4*)&Asd[row * BK + cp * 8] = pk;
        }
      }
    }
  };
  auto issueB = [&](int k0, unsigned short* Bsd) {
    #pragma unroll
    for (int t = 0; t < BITER; ++t) {
      int s = t * 256 + tid;
      int row = s >> 3, cp = s & 7, sc = cp ^ (row & 7);
      const unsigned short* src = Bp + (size_t)(n0 + row) * (size_t)ldb + k0 + sc * 8;
      __builtin_amdgcn_global_load_lds(
          (const __attribute__((address_space(1))) void*)src,
          (__attribute__((address_space(3))) void*)(Bsd + (size_t)(t * 256 + wid * 64) * 8),
          16, 0, 0);
    }
  };
  auto compute = [&](const unsigned short* Asd, const unsigned short* Bsd) {
    #pragma unroll
    for (int kk = 0; kk < 2; ++kk) {
      bf16x8 a[FM], b[FN];
      #pragma unroll
      for (int i = 0; i < FM; ++i) {
        int row = wr * WM + i * 16 + lr;
        int ch = (kk * 4 + g) ^ (row & 7);
        a[i] = *(const bf16x8*)&Asd[row * BK + ch * 8];
      }
      #pragma unroll
      for (int j = 0; j < FN; ++j) {
        int row = wc * WN + j * 16 + lr;
        int ch = (kk * 4 + g) ^ (row & 7);
        b[j] = *(const bf16x8*)&Bsd[row * BK + ch * 8];
      }
      #pragma unroll
      for (int i = 0; i < FM; ++i)
        #pragma unroll
        for (int j = 0; j < FN; ++j)
          acc[i][j] = __builtin_amdgcn_mfma_f32_16x16x32_bf16(a[i], b[j], acc[i][j], 0, 0, 0);
    }
  };

  // ---- prologue ----
  issueA(0, As0);
  issueB(0, Bs0);
  writeA(As0);
  __syncthreads();

  // ---- 2-phase main loop (nt even for all our shapes) ----
  const int nt = K / BK;
  for (int t = 0; t < nt; t += 2) {
    if (t + 1 < nt) { issueA((t + 1) * BK, As1); issueB((t + 1) * BK, Bs1); }
    compute(As0, Bs0);
    if (t + 1 < nt) writeA(As1);
    __syncthreads();
    {
      if (t + 2 < nt) { issueA((t + 2) * BK, As0); issueB((t + 2) * BK, Bs0); }
      compute(As1, Bs1);
      if (t + 2 < nt) writeA(As0);
      __syncthreads();
    }
  }

  // ---- epilogue ----
  const int rowb = wr * WM;
  const int colb = wc * WN;
  if constexpr (EPI == 0) {
    #pragma unroll
    for (int i = 0; i < FM; ++i) {
      int mrow = m0 + rowb + i * 16 + g * 4;
      #pragma unroll
      for (int j = 0; j < FN; ++j) {
        int col = n0 + colb + j * 16 + lr;
        #pragma unroll
        for (int r = 0; r < 4; ++r)
          Cf[(size_t)(mrow + r) * N + col] = acc[i][j][r];
      }
    }
  } else if constexpr (EPI == 1) {
    #pragma unroll
    for (int i = 0; i < FM; ++i) {
      int mrow = m0 + rowb + i * 16 + g * 4;
      #pragma unroll
      for (int j = 0; j < FN; ++j) {
        int col = n0 + colb + j * 16 + lr;
        ushort4 st;
        st.x = f2bf(acc[i][j][0]);
        st.y = f2bf(acc[i][j][1]);
        st.z = f2bf(acc[i][j][2]);
        st.w = f2bf(acc[i][j][3]);
        *(ushort4*)&Ct[(size_t)col * M + mrow] = st;
      }
    }
  } else {
    // symmetric fused d2 argmin; u32 keys: (f32bits(d2) & ~0x1FFF) | index
    const bool diag = (m0 == n0);
    int jcol[FN];
    float sqj[FN];
    unsigned colkey[FN];
    #pragma unroll
    for (int j = 0; j < FN; ++j) {
      jcol[j] = n0 + colb + j * 16 + lr;
      sqj[j] = sq[jcol[j]];
      colkey[j] = 0xFFFFFFFFu;
    }
    #pragma unroll
    for (int i = 0; i < FM; ++i) {
      #pragma unroll
      for (int r = 0; r < 4; ++r) {
        int irow = m0 + rowb + i * 16 + g * 4 + r;
        float sqi = sq[irow];
        unsigned rowkey = 0xFFFFFFFFu;
        #pragma unroll
        for (int j = 0; j < FN; ++j) {
          float d2 = sqi + sqj[j] - 2.0f * acc[i][j][r];
          unsigned db = __float_as_uint(d2) & 0xFFFFE000u;
          unsigned rk = db | (unsigned)jcol[j];
          if (diag && jcol[j] == irow) rk = 0xFFFFFFFFu;
          rowkey = min(rowkey, rk);
          if (!diag) colkey[j] = min(colkey[j], db | (unsigned)irow);
        }
        #pragma unroll
        for (int m = 1; m < 16; m <<= 1)
          rowkey = min(rowkey, (unsigned)__shfl_xor((int)rowkey, m, 64));
        if (lr == 0) atomicMin(&pck[irow], rowkey);
      }
    }
    if (!diag) {
      #pragma unroll
      for (int j = 0; j < FN; ++j) {
        colkey[j] = min(colkey[j], (unsigned)__shfl_xor((int)colkey[j], 16, 64));
        colkey[j] = min(colkey[j], (unsigned)__shfl_xor((int)colkey[j], 32, 64));
      }
      if (g == 0) {
        #pragma unroll
        for (int j = 0; j < FN; ++j) atomicMin(&pck[jcol[j]], colkey[j]);
      }
    }
  }
}

// ---------------- launch ----------------

extern "C" void kernel_launch(void* const* d_in, const int* in_sizes, int n_in,
                              void* d_out, int out_size, void* d_ws, size_t ws_size,
                              hipStream_t stream) {
  (void)in_sizes; (void)n_in; (void)out_size; (void)ws_size;
  const float* x   = (const float*)d_in[0];   // [4096][256]
  const float* adj = (const float*)d_in[1];   // [4096][4096]
  const float* W1  = (const float*)d_in[2];   // [256][256]
  const float* W2  = (const float*)d_in[3];   // [256][256]
  float* out = (float*)d_out;                 // [8192][256]

  char* p = (char*)d_ws;
  unsigned short* Tt       = (unsigned short*)p;  p += 4096 * 256 * 2;   // (x@W1)^T
  float* hbuf              = (float*)p;           p += 4096 * 256 * 4;   // adj@T
  unsigned short* x2b      = (unsigned short*)p;  p += 8192 * 256 * 2;   // upsampled bf16
  float* sqv               = (float*)p;           p += 8192 * 4;
  unsigned* pck            = (unsigned*)p;        p += 8192 * 4;
  float* support           = (float*)p;           p += 8192 * 256 * 4;
  unsigned short* W1t      = (unsigned short*)p;  p += 256 * 256 * 2;
  unsigned short* W2t      = (unsigned short*)p;  p += 256 * 256 * 2;

  hipMemsetAsync(pck, 0xFF, 8192 * 4, stream);
  transpose_w_kernel<<<256, 256, 0, stream>>>(W1, W2, W1t, W2t);

  // Tt = (x @ W1)^T : M=4096 N=256 K=256
  gemm_nt_kernel<128, 64, 4, 1, true><<<dim3(32, 4), 256, 0, stream>>>(
      x, 256, W1t, 256, 4096, 256, 256, nullptr, Tt, nullptr, nullptr);

  // h = adj @ T : M=4096 N=256 K=4096; BM=16 -> 256 blocks, adj read once
  gemm_nt_kernel<16, 256, 1, 0, true><<<dim3(256, 1), 256, 0, stream>>>(
      adj, 4096, Tt, 4096, 4096, 256, 4096, hbuf, nullptr, nullptr, nullptr);

  upsample_kernel<<<8192, 256, 0, stream>>>(hbuf, x2b, sqv);

  // Gram(x2) + fused symmetric argmin : lower triangle of 64x64 tile grid
  gemm_nt_kernel<128, 128, 2, 2, false><<<dim3(2080, 1), 256, 0, stream>>>(
      x2b, 256, x2b, 256, 8192, 8192, 256, nullptr, nullptr, sqv, pck);

  // support = x2 @ W2 : M=8192 N=256 K=256
  gemm_nt_kernel<128, 64, 4, 0, false><<<dim3(64, 4), 256, 0, stream>>>(
      x2b, 256, W2t, 256, 8192, 256, 256, support, nullptr, nullptr, nullptr);

  gather_kernel<<<2048, 256, 0, stream>>>(support, pck, out);
}

// Round 3
// 141.721 us; speedup vs baseline: 1.4600x; 1.0857x over previous
//
#include <hip/hip_runtime.h>
#include <hip/hip_bf16.h>
#include <cstdint>

typedef __attribute__((ext_vector_type(8))) __bf16 bf16x8;
typedef __attribute__((ext_vector_type(4))) float f32x4;

static __device__ __forceinline__ unsigned short f2bf(float f) {
  return __builtin_bit_cast(unsigned short, (__bf16)f);
}
static __device__ __forceinline__ float bf2f(unsigned short u) {
  return __builtin_bit_cast(float, ((unsigned)u) << 16);
}
static __device__ __forceinline__ unsigned pack2(float a, float b) {
  return (unsigned)f2bf(a) | ((unsigned)f2bf(b) << 16);
}

// ---------------- small prep kernels ----------------

__global__ void transpose_w_kernel(const float* __restrict__ W1, const float* __restrict__ W2,
                                   unsigned short* __restrict__ W1t, unsigned short* __restrict__ W2t) {
  int i = blockIdx.x * 256 + threadIdx.x;
  int k = i >> 8, n = i & 255;
  W1t[n * 256 + k] = f2bf(W1[k * 256 + n]);
  W2t[n * 256 + k] = f2bf(W2[k * 256 + n]);
}

// x2 = linear2x(sum of 4 bf16 K-split slices of h); emit bf16 x2 + row |.|^2
__global__ void upsample_kernel(const unsigned short* __restrict__ hs,  // [4][4096][256] bf16
                                unsigned short* __restrict__ x2b, float* __restrict__ sq) {
  int o = blockIdx.x;
  int c = threadIdx.x;
  float s = (o + 0.5f) * 0.5f - 0.5f;
  s = fminf(fmaxf(s, 0.0f), 4095.0f);
  float fl = floorf(s);
  int i0 = (int)fl;
  int i1 = min(i0 + 1, 4095);
  float w = s - fl;
  float v0 = 0.f, v1 = 0.f;
  #pragma unroll
  for (int k = 0; k < 4; ++k) {
    v0 += bf2f(hs[k * 4096 * 256 + i0 * 256 + c]);
    v1 += bf2f(hs[k * 4096 * 256 + i1 * 256 + c]);
  }
  float v = v0 * (1.0f - w) + v1 * w;
  x2b[o * 256 + c] = f2bf(v);
  float p = v * v;
  #pragma unroll
  for (int m = 32; m > 0; m >>= 1) p += __shfl_down(p, m, 64);
  __shared__ float red[4];
  if ((threadIdx.x & 63) == 0) red[threadIdx.x >> 6] = p;
  __syncthreads();
  if (threadIdx.x == 0) sq[o] = (red[0] + red[1]) + (red[2] + red[3]);
}

// final per-row lex-min over the 64 partial slots
__global__ void argmin_reduce_kernel(const float* __restrict__ pv,
                                     const unsigned* __restrict__ pidx,
                                     unsigned* __restrict__ pck) {
  int row = blockIdx.x * 256 + threadIdx.x;   // 8192
  float bv = 3.402823466e38f;
  unsigned bidx = 0;
  for (int c = 0; c < 64; ++c) {
    float v = pv[(size_t)c * 8192 + row];
    unsigned id = pidx[(size_t)c * 8192 + row];
    if (v < bv || (v == bv && id < bidx)) { bv = v; bidx = id; }
  }
  pck[row] = bidx;
}

__global__ void gather_kernel(const float* __restrict__ support,
                              const unsigned* __restrict__ pck,
                              float* __restrict__ out) {
  int gid = blockIdx.x * 256 + threadIdx.x;
  int row = gid >> 6;
  int c4 = (gid & 63) * 4;
  unsigned idx = pck[row];
  *(float4*)&out[(size_t)row * 256 + c4] = *(const float4*)&support[(size_t)idx * 256 + c4];
}

// ---------------- Gram + fused symmetric argmin (single-buffer, no atomics) ----
// X: [8192][256] bf16. Triangular grid over 64x64 chunk pairs (bi >= bj).
// Block computes G = Xi * Xj^T (128x128), then:
//   row-side: for each row r of chunk bi: min_j (sq[j] - 2G)  -> pv[bj][r]
//   col-side: for each col c of chunk bj: min_i (sq[i] - 2G)  -> pv[bi][c]  (skip if diag)
__launch_bounds__(256, 4)
__global__ void gram_argmin_kernel(const unsigned short* __restrict__ X,
                                   const float* __restrict__ sq,
                                   float* __restrict__ pv, unsigned* __restrict__ pidx) {
  constexpr int BK = 64;
  __shared__ alignas(16) unsigned short As[128 * BK];
  __shared__ alignas(16) unsigned short Bs[128 * BK];
  __shared__ float rvv[2][128];
  __shared__ unsigned rvi[2][128];
  __shared__ float cvv[2][128];
  __shared__ unsigned cvi[2][128];

  const int tid = threadIdx.x;
  const int wid = tid >> 6;
  const int lane = tid & 63;
  const int g = lane >> 4;
  const int lr = lane & 15;
  const int wr = wid >> 1;       // 2x2 waves, 64x64 per wave
  const int wc = wid & 1;

  int t = blockIdx.x;            // triangular decode, bj <= bi
  int bi = (int)((sqrtf(8.0f * (float)t + 1.0f) - 1.0f) * 0.5f);
  while ((bi + 1) * (bi + 2) / 2 <= t) ++bi;
  while (bi * (bi + 1) / 2 > t) --bi;
  const int bx = bi;
  const int by = t - bi * (bi + 1) / 2;
  const int m0 = bx * 128;
  const int n0 = by * 128;
  const bool diag = (bx == by);

  f32x4 acc[4][4];
  const f32x4 fzero = {0.0f, 0.0f, 0.0f, 0.0f};
  #pragma unroll
  for (int i = 0; i < 4; ++i)
    #pragma unroll
    for (int j = 0; j < 4; ++j) acc[i][j] = fzero;

  for (int k0 = 0; k0 < 256; k0 += BK) {
    #pragma unroll
    for (int it = 0; it < 4; ++it) {
      int s = it * 256 + tid;
      int row = s >> 3, cp = s & 7, sc = cp ^ (row & 7);
      __builtin_amdgcn_global_load_lds(
          (const __attribute__((address_space(1))) void*)(X + (size_t)(m0 + row) * 256 + k0 + sc * 8),
          (__attribute__((address_space(3))) void*)&As[(it * 256 + wid * 64) * 8], 16, 0, 0);
    }
    #pragma unroll
    for (int it = 0; it < 4; ++it) {
      int s = it * 256 + tid;
      int row = s >> 3, cp = s & 7, sc = cp ^ (row & 7);
      __builtin_amdgcn_global_load_lds(
          (const __attribute__((address_space(1))) void*)(X + (size_t)(n0 + row) * 256 + k0 + sc * 8),
          (__attribute__((address_space(3))) void*)&Bs[(it * 256 + wid * 64) * 8], 16, 0, 0);
    }
    __syncthreads();
    #pragma unroll
    for (int kk = 0; kk < 2; ++kk) {
      bf16x8 a[4], b[4];
      #pragma unroll
      for (int i = 0; i < 4; ++i) {
        int row = wr * 64 + i * 16 + lr;
        int ch = (kk * 4 + g) ^ (row & 7);
        a[i] = *(const bf16x8*)&As[row * BK + ch * 8];
      }
      #pragma unroll
      for (int j = 0; j < 4; ++j) {
        int row = wc * 64 + j * 16 + lr;
        int ch = (kk * 4 + g) ^ (row & 7);
        b[j] = *(const bf16x8*)&Bs[row * BK + ch * 8];
      }
      #pragma unroll
      for (int i = 0; i < 4; ++i)
        #pragma unroll
        for (int j = 0; j < 4; ++j)
          acc[i][j] = __builtin_amdgcn_mfma_f32_16x16x32_bf16(a[i], b[j], acc[i][j], 0, 0, 0);
    }
    __syncthreads();
  }

  // ---- epilogue: per-block partial argmin, no global atomics ----
  int jcol[4];
  float sqj[4], cval[4];
  unsigned cidx[4];
  #pragma unroll
  for (int j = 0; j < 4; ++j) {
    jcol[j] = n0 + wc * 64 + j * 16 + lr;
    sqj[j] = sq[jcol[j]];
    cval[j] = 3.402823466e38f;
    cidx[j] = 0;
  }
  #pragma unroll
  for (int i = 0; i < 4; ++i) {
    #pragma unroll
    for (int r = 0; r < 4; ++r) {
      int irow = m0 + wr * 64 + i * 16 + g * 4 + r;
      float sqi = sq[irow];
      float rval = 3.402823466e38f;
      unsigned ridx = 0;
      #pragma unroll
      for (int j = 0; j < 4; ++j) {
        float gv = acc[i][j][r];
        float rv = fmaf(-2.0f, gv, sqj[j]);    // query row irow: sq[i] const dropped
        if (diag && jcol[j] == irow) rv = 3.402823466e38f;
        if (rv < rval) { rval = rv; ridx = (unsigned)jcol[j]; }   // j ascending
        float cv = fmaf(-2.0f, gv, sqi);       // query col jcol[j]
        if (cv < cval[j] || (cv == cval[j] && (unsigned)irow < cidx[j])) {
          cval[j] = cv; cidx[j] = (unsigned)irow;
        }
      }
      #pragma unroll
      for (int m = 1; m < 16; m <<= 1) {
        float vo = __shfl_xor(rval, m, 64);
        unsigned io = (unsigned)__shfl_xor((int)ridx, m, 64);
        if (vo < rval || (vo == rval && io < ridx)) { rval = vo; ridx = io; }
      }
      if (lr == 0) {
        int rl = wr * 64 + i * 16 + g * 4 + r;
        rvv[wc][rl] = rval;
        rvi[wc][rl] = ridx;
      }
    }
  }
  if (!diag) {
    #pragma unroll
    for (int j = 0; j < 4; ++j) {
      #pragma unroll
      for (int m = 16; m < 64; m <<= 1) {
        float vo = __shfl_xor(cval[j], m, 64);
        unsigned io = (unsigned)__shfl_xor((int)cidx[j], m, 64);
        if (vo < cval[j] || (vo == cval[j] && io < cidx[j])) { cval[j] = vo; cidx[j] = io; }
      }
      if (g == 0) {
        int cl = wc * 64 + j * 16 + lr;
        cvv[wr][cl] = cval[j];
        cvi[wr][cl] = cidx[j];
      }
    }
  }
  __syncthreads();
  if (tid < 128) {
    float v0 = rvv[0][tid], v1 = rvv[1][tid];
    unsigned i0 = rvi[0][tid], i1 = rvi[1][tid];
    bool take1 = (v1 < v0) || (v1 == v0 && i1 < i0);
    pv[(size_t)by * 8192 + m0 + tid] = take1 ? v1 : v0;
    pidx[(size_t)by * 8192 + m0 + tid] = take1 ? i1 : i0;
  } else if (!diag) {
    int c = tid - 128;
    float v0 = cvv[0][c], v1 = cvv[1][c];
    unsigned i0 = cvi[0][c], i1 = cvi[1][c];
    bool take1 = (v1 < v0) || (v1 == v0 && i1 < i0);
    pv[(size_t)bx * 8192 + n0 + c] = take1 ? v1 : v0;
    pidx[(size_t)bx * 8192 + n0 + c] = take1 ? i1 : i0;
  }
}

// ---------------- GEMM-NT (C = A * B^T), bf16 MFMA, 2-phase pipelined ----------
// A: [M][K] (fp32 if AF32 else bf16), lda=K. B: [N][K] bf16, ldb=K.
// EPI 0: Cf[m][n] fp32 (n0 = by*BN).
// EPI 1: Ct[n][m] bf16 transposed store (n0 = by*BN).
// EPI 3: Cb[m][n] bf16, K-split: by = k-slice (kbase = by*K, out += by*M*N), n0 = 0.
template <int BM, int BN, int WAVES_M, int EPI, bool AF32>
__launch_bounds__(256)
__global__ void gemm_nt_kernel(const void* __restrict__ Ap, int lda,
                               const unsigned short* __restrict__ Bp, int ldb,
                               int M, int N, int K,
                               float* __restrict__ Cf,
                               unsigned short* __restrict__ Cb) {
  constexpr int BK = 64;
  constexpr int WAVES_N = 4 / WAVES_M;
  constexpr int WM = BM / WAVES_M;
  constexpr int WN = BN / WAVES_N;
  constexpr int FM = WM / 16;
  constexpr int FN = WN / 16;
  constexpr int ASLOT = BM * 8;
  constexpr int AITER = (ASLOT + 255) / 256;
  constexpr int BITER = (BN * 8) / 256;

  __shared__ alignas(16) unsigned short As0[BM * BK], As1[BM * BK];
  __shared__ alignas(16) unsigned short Bs0[BN * BK], Bs1[BN * BK];

  const int tid = threadIdx.x;
  const int wid = tid >> 6;
  const int lane = tid & 63;
  const int g = lane >> 4;
  const int lr = lane & 15;
  const int wr = wid / WAVES_N;
  const int wc = wid % WAVES_N;
  const int m0 = blockIdx.x * BM;
  const int n0 = (EPI == 3) ? 0 : blockIdx.y * BN;
  const int kbase = (EPI == 3) ? blockIdx.y * K : 0;
  if constexpr (EPI == 3) Cb += (size_t)blockIdx.y * (size_t)M * (size_t)N;

  f32x4 acc[FM][FN];
  const f32x4 fzero = {0.0f, 0.0f, 0.0f, 0.0f};
  #pragma unroll
  for (int i = 0; i < FM; ++i)
    #pragma unroll
    for (int j = 0; j < FN; ++j) acc[i][j] = fzero;

  float4 ar[AITER][2];

  auto issueA = [&](int k0, unsigned short* Asd) {
    if constexpr (AF32) {
      const float* A = (const float*)Ap;
      #pragma unroll
      for (int it = 0; it < AITER; ++it) {
        int s = it * 256 + tid;
        if (ASLOT % 256 == 0 || s < ASLOT) {
          int row = s >> 3, cp = s & 7, sc = cp ^ (row & 7);
          const float* src = A + (size_t)(m0 + row) * (size_t)lda + kbase + k0 + sc * 8;
          ar[it][0] = *(const float4*)src;
          ar[it][1] = *(const float4*)(src + 4);
        }
      }
    } else {
      const unsigned short* A = (const unsigned short*)Ap;
      #pragma unroll
      for (int it = 0; it < AITER; ++it) {
        int s = it * 256 + tid;
        int row = s >> 3, cp = s & 7, sc = cp ^ (row & 7);
        const unsigned short* src = A + (size_t)(m0 + row) * (size_t)lda + kbase + k0 + sc * 8;
        __builtin_amdgcn_global_load_lds(
            (const __attribute__((address_space(1))) void*)src,
            (__attribute__((address_space(3))) void*)(Asd + (size_t)(it * 256 + wid * 64) * 8),
            16, 0, 0);
      }
    }
  };
  auto writeA = [&](unsigned short* Asd) {
    if constexpr (AF32) {
      #pragma unroll
      for (int it = 0; it < AITER; ++it) {
        int s = it * 256 + tid;
        if (ASLOT % 256 == 0 || s < ASLOT) {
          int row = s >> 3, cp = s & 7;
          uint4 pk = { pack2(ar[it][0].x, ar[it][0].y), pack2(ar[it][0].z, ar[it][0].w),
                       pack2(ar[it][1].x, ar[it][1].y), pack2(ar[it][1].z, ar[it][1].w) };
          *(uint4*)&Asd[row * BK + cp * 8] = pk;
        }
      }
    }
  };
  auto issueB = [&](int k0, unsigned short* Bsd) {
    #pragma unroll
    for (int it = 0; it < BITER; ++it) {
      int s = it * 256 + tid;
      int row = s >> 3, cp = s & 7, sc = cp ^ (row & 7);
      const unsigned short* src = Bp + (size_t)(n0 + row) * (size_t)ldb + kbase + k0 + sc * 8;
      __builtin_amdgcn_global_load_lds(
          (const __attribute__((address_space(1))) void*)src,
          (__attribute__((address_space(3))) void*)(Bsd + (size_t)(it * 256 + wid * 64) * 8),
          16, 0, 0);
    }
  };
  auto compute = [&](const unsigned short* Asd, const unsigned short* Bsd) {
    #pragma unroll
    for (int kk = 0; kk < 2; ++kk) {
      bf16x8 a[FM], b[FN];
      #pragma unroll
      for (int i = 0; i < FM; ++i) {
        int row = wr * WM + i * 16 + lr;
        int ch = (kk * 4 + g) ^ (row & 7);
        a[i] = *(const bf16x8*)&Asd[row * BK + ch * 8];
      }
      #pragma unroll
      for (int j = 0; j < FN; ++j) {
        int row = wc * WN + j * 16 + lr;
        int ch = (kk * 4 + g) ^ (row & 7);
        b[j] = *(const bf16x8*)&Bsd[row * BK + ch * 8];
      }
      #pragma unroll
      for (int i = 0; i < FM; ++i)
        #pragma unroll
        for (int j = 0; j < FN; ++j)
          acc[i][j] = __builtin_amdgcn_mfma_f32_16x16x32_bf16(a[i], b[j], acc[i][j], 0, 0, 0);
    }
  };

  issueA(0, As0);
  issueB(0, Bs0);
  writeA(As0);
  __syncthreads();

  const int nt = K / BK;
  for (int t = 0; t < nt; t += 2) {
    if (t + 1 < nt) { issueA((t + 1) * BK, As1); issueB((t + 1) * BK, Bs1); }
    compute(As0, Bs0);
    if (t + 1 < nt) writeA(As1);
    __syncthreads();
    if (t + 2 < nt) { issueA((t + 2) * BK, As0); issueB((t + 2) * BK, Bs0); }
    compute(As1, Bs1);
    if (t + 2 < nt) writeA(As0);
    __syncthreads();
  }

  const int rowb = wr * WM;
  const int colb = wc * WN;
  if constexpr (EPI == 0) {
    #pragma unroll
    for (int i = 0; i < FM; ++i) {
      int mrow = m0 + rowb + i * 16 + g * 4;
      #pragma unroll
      for (int j = 0; j < FN; ++j) {
        int col = n0 + colb + j * 16 + lr;
        #pragma unroll
        for (int r = 0; r < 4; ++r)
          Cf[(size_t)(mrow + r) * N + col] = acc[i][j][r];
      }
    }
  } else if constexpr (EPI == 1) {
    #pragma unroll
    for (int i = 0; i < FM; ++i) {
      int mrow = m0 + rowb + i * 16 + g * 4;
      #pragma unroll
      for (int j = 0; j < FN; ++j) {
        int col = n0 + colb + j * 16 + lr;
        ushort4 st;
        st.x = f2bf(acc[i][j][0]);
        st.y = f2bf(acc[i][j][1]);
        st.z = f2bf(acc[i][j][2]);
        st.w = f2bf(acc[i][j][3]);
        *(ushort4*)&Cb[(size_t)col * M + mrow] = st;
      }
    }
  } else {
    #pragma unroll
    for (int i = 0; i < FM; ++i) {
      int mrow = m0 + rowb + i * 16 + g * 4;
      #pragma unroll
      for (int j = 0; j < FN; ++j) {
        int col = n0 + colb + j * 16 + lr;
        #pragma unroll
        for (int r = 0; r < 4; ++r)
          Cb[(size_t)(mrow + r) * N + col] = f2bf(acc[i][j][r]);
      }
    }
  }
}

// ---------------- launch ----------------

extern "C" void kernel_launch(void* const* d_in, const int* in_sizes, int n_in,
                              void* d_out, int out_size, void* d_ws, size_t ws_size,
                              hipStream_t stream) {
  (void)in_sizes; (void)n_in; (void)out_size; (void)ws_size;
  const float* x   = (const float*)d_in[0];   // [4096][256]
  const float* adj = (const float*)d_in[1];   // [4096][4096]
  const float* W1  = (const float*)d_in[2];   // [256][256]
  const float* W2  = (const float*)d_in[3];   // [256][256]
  float* out = (float*)d_out;                 // [8192][256]

  char* p = (char*)d_ws;
  unsigned short* Tt  = (unsigned short*)p;  p += 4096 * 256 * 2;     // 2MB  (x@W1)^T [256][4096]
  char* R             = p;                   p += 8 * 1024 * 1024;    // 8MB shared-lifetime region
  unsigned short* x2b = (unsigned short*)p;  p += 8192 * 256 * 2;     // 4MB
  float* sqv          = (float*)p;           p += 8192 * 4;
  unsigned* pck       = (unsigned*)p;        p += 8192 * 4;
  unsigned short* W1t = (unsigned short*)p;  p += 256 * 256 * 2;
  unsigned short* W2t = (unsigned short*)p;  p += 256 * 256 * 2;

  // region R overlays (disjoint lifetimes):
  unsigned short* hs = (unsigned short*)R;                  // [4][4096][256] bf16 (adj-gemm -> upsample)
  float* pv          = (float*)R;                           // [64][8192] f32 (gram -> reduce)
  unsigned* pidx     = (unsigned*)(R + 2 * 1024 * 1024);    // [64][8192] u32
  float* support     = (float*)R;                           // [8192][256] f32 (support-gemm -> gather)

  transpose_w_kernel<<<256, 256, 0, stream>>>(W1, W2, W1t, W2t);

  // Tt = (x @ W1)^T : M=4096 N=256 K=256 -> 256 blocks
  gemm_nt_kernel<64, 64, 4, 1, true><<<dim3(64, 4), 256, 0, stream>>>(
      x, 256, W1t, 256, 4096, 256, 256, nullptr, Tt);

  // h(k-split) = adj @ T : M=4096 N=256, split K=4096 into 4x1024 -> 1024 blocks
  gemm_nt_kernel<16, 256, 1, 3, true><<<dim3(256, 4), 256, 0, stream>>>(
      adj, 4096, Tt, 4096, 4096, 256, 1024, nullptr, hs);

  upsample_kernel<<<8192, 256, 0, stream>>>(hs, x2b, sqv);

  // Gram + fused symmetric argmin partials: triangle of 64x64 chunk grid
  gram_argmin_kernel<<<2080, 256, 0, stream>>>(x2b, sqv, pv, pidx);

  argmin_reduce_kernel<<<32, 256, 0, stream>>>(pv, pidx, pck);

  // support = x2 @ W2 : M=8192 N=256 K=256 -> 512 blocks
  gemm_nt_kernel<64, 64, 4, 0, false><<<dim3(128, 4), 256, 0, stream>>>(
      x2b, 256, W2t, 256, 8192, 256, 256, support, nullptr);

  gather_kernel<<<2048, 256, 0, stream>>>(support, pck, out);
}